// Round 11
// baseline (150.536 us; speedup 1.0000x reference)
//
#include <hip/hip_runtime.h>
#include <hip/hip_bf16.h>
#include <type_traits>
#include <stdint.h>

// ---- problem constants ----
static constexpr int BB   = 4;
static constexpr int SS   = 1024;
static constexpr int HH   = 32;
static constexpr int HKV  = 8;
static constexpr int GG   = 4;      // H / HKV
static constexpr int DD   = 128;
static constexpr int PAGE = 128;    // paged-cache block size
static constexpr int NBLK = 64;     // cache blocks
static constexpr int KVB  = 32;     // kv rows per tile
static constexpr int NT   = SS / KVB;   // 32 kv tiles per (b,hkv)
static constexpr int TB   = 8192;   // packed tile bytes ([32 rows][256B])

typedef __attribute__((ext_vector_type(8)))  short    s16x8;
typedef __attribute__((ext_vector_type(8)))  __bf16   b16x8;
typedef __attribute__((ext_vector_type(16))) float    f32x16;
typedef __attribute__((ext_vector_type(4)))  unsigned u32x4;

// ---- MFMA wrapper: compiles whether the builtin takes short8 or bf16x8 ----
template <typename T>
__device__ __forceinline__ auto mfma_try(T a, T b, f32x16 c, int)
    -> decltype(__builtin_amdgcn_mfma_f32_32x32x16_bf16(a, b, c, 0, 0, 0)) {
  return __builtin_amdgcn_mfma_f32_32x32x16_bf16(a, b, c, 0, 0, 0);
}
template <typename T>
__device__ __forceinline__ f32x16 mfma_try(T a, T b, f32x16 c, long) {
  using O = typename std::conditional<std::is_same<T, s16x8>::value, b16x8, s16x8>::type;
  return __builtin_amdgcn_mfma_f32_32x32x16_bf16(
      __builtin_bit_cast(O, a), __builtin_bit_cast(O, b), c, 0, 0, 0);
}
__device__ __forceinline__ f32x16 mfma32_bf16(s16x8 a, s16x8 b, f32x16 c) {
  return mfma_try(a, b, c, 0);
}

__device__ __forceinline__ short bfb(float x) {
  return (short)__builtin_bit_cast(unsigned short, (__bf16)x);
}
__device__ __forceinline__ unsigned pack_bf16x2(float a, float b) {
  unsigned ua = (unsigned short)__builtin_bit_cast(unsigned short, (__bf16)a);
  unsigned ub = (unsigned short)__builtin_bit_cast(unsigned short, (__bf16)b);
  return ua | (ub << 16);
}
__device__ __forceinline__ f32x16 zero16() {
  f32x16 z;
#pragma unroll
  for (int i = 0; i < 16; ++i) z[i] = 0.0f;
  return z;
}
__device__ __forceinline__ void gload16(const unsigned char* g, unsigned char* l) {
  __builtin_amdgcn_global_load_lds(
      (const __attribute__((address_space(1))) unsigned*)g,
      (__attribute__((address_space(3))) unsigned*)(unsigned*)l, 16, 0, 0);
}
#define VC(a, i) ((i)==0?(a).x:(i)==1?(a).y:(i)==2?(a).z:(a).w)

// =====================================================================
// Kernel 0: pre-pack K and V into SWIZZLED bf16 tiles (KVB=32) in d_ws.
//  (unchanged — verified R5-R10)
// =====================================================================
__global__ void __launch_bounds__(256)
pack_kv_kernel(const float* __restrict__ k_in, const float* __restrict__ v_in,
               unsigned char* __restrict__ kpk, unsigned char* __restrict__ vpk)
{
  __shared__ __align__(16) unsigned char Vt[DD * 176];  // [d][64 kv], stride 176B

  const int wg  = blockIdx.x;          // (b*HKV+hkv)*16 + t64
  const int t64 = wg & 15;
  const int bh  = wg >> 4;             // b*HKV + hkv
  const int tid = threadIdx.x;
  const int row = tid >> 2, c = tid & 3;

  const size_t srow = ((size_t)(bh >> 3) * SS + t64 * 64 + row) * (HKV * DD)
                    + (size_t)(bh & 7) * DD + c * 32;
  const size_t tb0 = ((size_t)bh * NT + t64 * 2) * (size_t)TB;

  // ---- K: bf16 pack, swizzled chunk placement ----
  {
    const float* ks = k_in + srow;
    const int t2 = row >> 5, r32 = row & 31;
    unsigned char* kd = kpk + tb0 + t2 * TB + r32 * 256;
#pragma unroll
    for (int j = 0; j < 4; ++j) {
      const float4 f0 = *(const float4*)(ks + j * 8);
      const float4 f1 = *(const float4*)(ks + j * 8 + 4);
      s16x8 kb;
      kb[0]=bfb(f0.x); kb[1]=bfb(f0.y); kb[2]=bfb(f0.z); kb[3]=bfb(f0.w);
      kb[4]=bfb(f1.x); kb[5]=bfb(f1.y); kb[6]=bfb(f1.z); kb[7]=bfb(f1.w);
      *(s16x8*)(kd + (((c * 4 + j) ^ (r32 & 15)) << 4)) = kb;
    }
  }
  // ---- V: transpose via LDS ----
  {
    const float* vs = v_in + srow;
    float4 va[8];
#pragma unroll
    for (int jj = 0; jj < 8; ++jj) va[jj] = *(const float4*)(vs + jj * 4);
#pragma unroll
    for (int jj = 0; jj < 8; ++jj)
#pragma unroll
      for (int e = 0; e < 4; ++e) {
        const int d = c * 32 + jj * 4 + e;
        *(short*)(Vt + d * 176 + row * 2) = bfb(VC(va[jj], e));
      }
  }
  __syncthreads();
  {
    const int t2 = tid & 1, r = (tid >> 1) & 31, q = tid >> 6;
    unsigned char* vd = vpk + tb0 + t2 * TB + r * 256;
#pragma unroll
    for (int jj = 0; jj < 4; ++jj) {
      const int lc = q * 4 + jj;
      const int d  = (lc >> 2) * 32 + r;
      const float4 chunk = *(const float4*)(Vt + d * 176 + t2 * 64 + (lc & 3) * 16);
      *(float4*)(vd + ((lc ^ (r & 15)) << 4)) = chunk;
    }
  }
}

// =====================================================================
// Kernel 1: paged KV-cache update (exact fp32 copy).  (R4-verified)
// =====================================================================
__global__ void __launch_bounds__(256)
cache_scatter_kernel(const float* __restrict__ k_in, const float* __restrict__ v_in,
                     const float* __restrict__ kc_in, const float* __restrict__ vc_in,
                     const int* __restrict__ bidx, int n_used,
                     float* __restrict__ kc_out, float* __restrict__ vc_out)
{
  const int BLK_ELEMS = PAGE * HKV * DD;
  const int wg    = blockIdx.x;
  const int chunk = wg & 7;
  const int which = (wg >> 3) & 1;
  const int cb    = wg >> 4;

  int src_blk = -1;
  for (int i = 0; i < n_used; ++i)
    if (bidx[i] == cb) src_blk = i;        // last match wins

  const float* src;
  float* dst;
  if (which == 0) {
    src = (src_blk >= 0) ? (k_in + (size_t)src_blk * BLK_ELEMS)
                         : (kc_in + (size_t)cb * BLK_ELEMS);
    dst = kc_out + (size_t)cb * BLK_ELEMS;
  } else {
    src = (src_blk >= 0) ? (v_in + (size_t)src_blk * BLK_ELEMS)
                         : (vc_in + (size_t)cb * BLK_ELEMS);
    dst = vc_out + (size_t)cb * BLK_ELEMS;
  }
  const int CHUNK = BLK_ELEMS / 8;
  const float4* s4 = (const float4*)(src + chunk * CHUNK);
  float4*       d4 = (float4*)(dst + chunk * CHUNK);
#pragma unroll 4
  for (int i = threadIdx.x; i < CHUNK / 4; i += 256) d4[i] = s4[i];
}

// =====================================================================
// Kernel 2: causal + ALiBi GQA prefill attention, bf16 MFMA 32x32x16.
// Each wave owns 64 q rows (blocks A=rows[0,32), B=rows[32,64)); K/V
// fragments read from LDS ONCE per phase feed both blocks (half the
// LDS traffic, 2x MFMA per read).  QBLK=256, qt in {0..3}, grid 512
// (2 wg/CU), qt map (3,2,0,1) by quarter -> co-resident pairs ~(3,0)/(2,1).
// R9-verified pipeline: 3-buffer LDS, prefetch distance 2, counted
// vmcnt(4) + raw s_barrier per phase.
// =====================================================================
__global__ void __launch_bounds__(256, 2)
attn_kernel(const float* __restrict__ q_in,
            const unsigned char* __restrict__ kpk,
            const unsigned char* __restrict__ vpk,
            const float* __restrict__ slopes, float* __restrict__ out)
{
  __shared__ __align__(16) unsigned char K_lds[3][TB];  // 3 x 8 KB
  __shared__ __align__(16) unsigned char V_lds[3][TB];  // 3 x 8 KB

  const int n   = blockIdx.x;            // 0..511
  const int tid = threadIdx.x;
  const int q2  = n >> 7;                // quarter 0..3
  const int qt  = (q2 == 0) ? 3 : (q2 == 1) ? 2 : (q2 == 2) ? 0 : 1;
  const int id  = n & 127;
  const int hc  = (id & 7) * 16 + (id >> 3);   // XCD-aware head-combo
  const int b   = hc >> 5;
  const int hkv = (hc >> 2) & 7;
  const int g   = hc & 3;
  const int h   = hkv * GG + g;

  const int w    = tid >> 6;
  const int lane = tid & 63;
  const int ln   = lane & 31;
  const int hi   = lane >> 5;

  const float LOG2E  = 1.44269504088896340736f;
  const float QSCALE = 0.08838834764831845f * LOG2E;
  const float slope2 = slopes[h] * LOG2E;

  // staging roles: waves 0,1 -> K halves; waves 2,3 -> V halves (4 loads/tile)
  const size_t bh_off = (size_t)(b * HKV + hkv) * NT * (size_t)TB;
  const int role_v = w >> 1, halfid = w & 1;
  const unsigned char* gsrc = (role_v ? vpk : kpk) + bh_off
                            + halfid * 4096 + (size_t)lane * 16;
  unsigned char* ldst = (role_v ? &V_lds[0][0] : &K_lds[0][0])
                      + halfid * 4096 + lane * 16;

  const int nt = 8 * qt + 8;             // kv tiles this wg covers

#define STAGE_T(T, B) do { if ((T) < nt) {                                 \
    const unsigned char* g_ = gsrc + (size_t)(T) * TB;                     \
    unsigned char* l_ = ldst + (B) * TB;                                   \
    gload16(g_, l_);               gload16(g_ + 1024, l_ + 1024);          \
    gload16(g_ + 2048, l_ + 2048); gload16(g_ + 3072, l_ + 3072); } } while(0)

  const int lnbase = ln * 256;
  const int lnsw   = (ln & 15) << 4;
  const int hib    = hi * 16;

  const int qw0   = qt * 256 + w * 64;   // wave's first q row (block A)
  const int qgA   = qw0 + ln;
  const int qgB   = qw0 + 32 + ln;
  const int tmaxA = 8 * qt + 2 * w;      // == tdiagA
  const int tmaxB = tmaxA + 1;           // == tdiagB
  const size_t bs_off = (size_t)b * SS;

  // ---- Q fragments for BOTH blocks, pre-scaled, loaded up-front ----
  s16x8 qfragA[8], qfragB[8];
#define LOADQ(QF, QG) do {                                                 \
    const float* qrow_ = q_in + ((bs_off + (QG)) * HH + h) * DD;           \
    _Pragma("unroll")                                                      \
    for (int ks = 0; ks < 8; ++ks) {                                       \
      const float4 f0 = *(const float4*)(qrow_ + ks * 16 + hi * 8);        \
      const float4 f1 = *(const float4*)(qrow_ + ks * 16 + hi * 8 + 4);    \
      s16x8 qv;                                                            \
      qv[0] = bfb(f0.x * QSCALE); qv[1] = bfb(f0.y * QSCALE);              \
      qv[2] = bfb(f0.z * QSCALE); qv[3] = bfb(f0.w * QSCALE);              \
      qv[4] = bfb(f1.x * QSCALE); qv[5] = bfb(f1.y * QSCALE);              \
      qv[6] = bfb(f1.z * QSCALE); qv[7] = bfb(f1.w * QSCALE);              \
      QF[ks] = qv;                                                         \
    } } while(0)
  LOADQ(qfragA, qgA);
  LOADQ(qfragB, qgB);
  asm volatile("s_waitcnt vmcnt(0)" ::: "memory");   // exact vmcnt bookkeeping

  f32x16 accA[4], accB[4];
#pragma unroll
  for (int m = 0; m < 4; ++m) { accA[m] = zero16(); accB[m] = zero16(); }
  float mrunA = -INFINITY, lrunA = 0.0f;
  float mrunB = -INFINITY, lrunB = 0.0f;

// ---- softmax for one block (bias already applied, mask optional) ----
#define SOFTMAX1(SC, MRUN, LRUN, ACC) do {                                 \
    const float a0 = fmaxf(fmaxf(SC[0], SC[1]), SC[2]);                    \
    const float a1 = fmaxf(fmaxf(SC[3], SC[4]), SC[5]);                    \
    const float a2 = fmaxf(fmaxf(SC[6], SC[7]), SC[8]);                    \
    const float a3 = fmaxf(fmaxf(SC[9], SC[10]), SC[11]);                  \
    const float a4 = fmaxf(fmaxf(SC[12], SC[13]), SC[14]);                 \
    const float bm0 = fmaxf(fmaxf(a0, a1), SC[15]);                        \
    const float bm1 = fmaxf(fmaxf(a2, a3), a4);                            \
    float pm = fmaxf(bm0, bm1);                                            \
    pm = fmaxf(pm, __shfl_xor(pm, 32));                                    \
    if (!__all(pm <= MRUN + 8.0f)) {                                       \
      const float mnew = fmaxf(MRUN, pm);                                  \
      const float fac  = __builtin_exp2f(MRUN - mnew);                     \
      LRUN *= fac;                                                         \
      _Pragma("unroll")                                                    \
      for (int m = 0; m < 4; ++m)                                          \
        _Pragma("unroll")                                                  \
        for (int r = 0; r < 16; ++r) ACC[m][r] *= fac;                     \
      MRUN = mnew;                                                         \
    }                                                                      \
    _Pragma("unroll")                                                      \
    for (int r = 0; r < 16; ++r) SC[r] = __builtin_exp2f(SC[r] - MRUN);    \
    float s8[8];                                                           \
    _Pragma("unroll")                                                      \
    for (int i = 0; i < 8; ++i) s8[i] = SC[i] + SC[i + 8];                 \
    _Pragma("unroll")                                                      \
    for (int i = 0; i < 4; ++i) s8[i] = s8[i] + s8[i + 4];                 \
    float rs = (s8[0] + s8[1]) + (s8[2] + s8[3]);                          \
    rs += __shfl_xor(rs, 32);                                              \
    LRUN += rs;                                                            \
  } while(0)

// ---- build P fragment (4 words) for block from exp'd SC ----
#define PFRAG(SC, KS2, FW) do {                                            \
    const unsigned u0 = pack_bf16x2(SC[8*(KS2)+0], SC[8*(KS2)+1]);         \
    const unsigned u1 = pack_bf16x2(SC[8*(KS2)+2], SC[8*(KS2)+3]);         \
    const unsigned u2 = pack_bf16x2(SC[8*(KS2)+4], SC[8*(KS2)+5]);         \
    const unsigned u3 = pack_bf16x2(SC[8*(KS2)+6], SC[8*(KS2)+7]);         \
    const unsigned aa0 = hi ? u0 : u2;                                     \
    const unsigned aa1 = hi ? u1 : u3;                                     \
    const unsigned x0 = __shfl_xor(aa0, 32);                               \
    const unsigned x1 = __shfl_xor(aa1, 32);                               \
    FW[0] = hi ? x0 : u0;  FW[1] = hi ? x1 : u1;                           \
    FW[2] = hi ? u2 : x0;  FW[3] = hi ? u3 : x1;                           \
  } while(0)

#define APPLY_BIAS(SC) do {                                                \
    _Pragma("unroll")                                                      \
    for (int r = 0; r < 16; ++r) {                                         \
      const float patc = (float)((r & 3) + 8 * (r >> 2));                  \
      SC[r] = __builtin_fmaf(slope2, kbasef + patc, SC[r]);                \
    } } while(0)

#define APPLY_MASK(SC) do {                                                \
    _Pragma("unroll")                                                      \
    for (int r = 0; r < 16; ++r) {                                         \
      const int pat = (r & 3) + 8 * (r >> 2) + 4 * hi;                     \
      SC[r] = (pat <= ln) ? SC[r] : -INFINITY;                             \
    } } while(0)

  // ---- prologue: two tiles in flight ----
  STAGE_T(0, 0);
  STAGE_T(1, 1);

  int b0 = 0;
  for (int t = 0; t < nt; ++t) {
    if (t + 1 < nt) asm volatile("s_waitcnt vmcnt(4)" ::: "memory");
    else            asm volatile("s_waitcnt vmcnt(0)" ::: "memory");
    __builtin_amdgcn_s_barrier();        // publish LDS; all waves in phase t
    __builtin_amdgcn_sched_barrier(0);   // no ds_read hoisting above barrier

    int b2 = b0 + 2; if (b2 >= 3) b2 -= 3;
    STAGE_T(t + 2, b2);                  // buf freed by phase t-1

    const unsigned char* kb = &K_lds[0][0] + b0 * TB;
    const unsigned char* vb = &V_lds[0][0] + b0 * TB;
    const float kbasef = (float)(t * KVB + 4 * hi);

    if (t <= tmaxA) {
      // ======== both blocks active: shared K/V reads, dual chains ========
      f32x16 sA, sB;
      {
        f32x16 aA = zero16(), aB = zero16();
        const unsigned char* krow = kb + lnbase;
        __builtin_amdgcn_s_setprio(1);
#pragma unroll
        for (int ks = 0; ks < 8; ++ks) {
          const s16x8 af = *(const s16x8*)(krow + ((ks * 32 + hib) ^ lnsw));
          aA = mfma32_bf16(af, qfragA[ks], aA);
          aB = mfma32_bf16(af, qfragB[ks], aB);
        }
        __builtin_amdgcn_s_setprio(0);
        sA = aA; sB = aB;
      }
      APPLY_BIAS(sA);
      APPLY_BIAS(sB);
      if (t == tmaxA) APPLY_MASK(sA);    // A's diagonal (B's is next tile)
      SOFTMAX1(sA, mrunA, lrunA, accA);
      SOFTMAX1(sB, mrunB, lrunB, accB);

      __builtin_amdgcn_s_setprio(1);
#pragma unroll
      for (int ks2 = 0; ks2 < 2; ++ks2) {
        unsigned fwA[4], fwB[4];
        PFRAG(sA, ks2, fwA);
        PFRAG(sB, ks2, fwB);
        const u32x4 vA = {fwA[0], fwA[1], fwA[2], fwA[3]};
        const u32x4 vB = {fwB[0], fwB[1], fwB[2], fwB[3]};
        const s16x8 pfA = __builtin_bit_cast(s16x8, vA);
        const s16x8 pfB = __builtin_bit_cast(s16x8, vB);
#pragma unroll
        for (int m = 0; m < 4; ++m) {
          const s16x8 vf = *(const s16x8*)(vb + lnbase +
                               ((m * 64 + ks2 * 32 + hib) ^ lnsw));
          accA[m] = mfma32_bf16(vf, pfA, accA[m]);
          accB[m] = mfma32_bf16(vf, pfB, accB[m]);
        }
      }
      __builtin_amdgcn_s_setprio(0);
    } else if (t <= tmaxB) {
      // ======== B-only phase (B's diagonal tile) ========
      f32x16 sB;
      {
        f32x16 aB = zero16();
        const unsigned char* krow = kb + lnbase;
        __builtin_amdgcn_s_setprio(1);
#pragma unroll
        for (int ks = 0; ks < 8; ++ks) {
          const s16x8 af = *(const s16x8*)(krow + ((ks * 32 + hib) ^ lnsw));
          aB = mfma32_bf16(af, qfragB[ks], aB);
        }
        __builtin_amdgcn_s_setprio(0);
        sB = aB;
      }
      APPLY_BIAS(sB);
      APPLY_MASK(sB);                    // t == tdiagB always here
      SOFTMAX1(sB, mrunB, lrunB, accB);

      __builtin_amdgcn_s_setprio(1);
#pragma unroll
      for (int ks2 = 0; ks2 < 2; ++ks2) {
        unsigned fwB[4];
        PFRAG(sB, ks2, fwB);
        const u32x4 vB = {fwB[0], fwB[1], fwB[2], fwB[3]};
        const s16x8 pfB = __builtin_bit_cast(s16x8, vB);
#pragma unroll
        for (int m = 0; m < 4; ++m) {
          const s16x8 vf = *(const s16x8*)(vb + lnbase +
                               ((m * 64 + ks2 * 32 + hib) ^ lnsw));
          accB[m] = mfma32_bf16(vf, pfB, accB[m]);
        }
      }
      __builtin_amdgcn_s_setprio(0);
    }

    b0 = (b0 + 1 == 3) ? 0 : b0 + 1;
  }

  // ---- epilogues: O = O^T / l for both blocks ----
#define EPILOG(ACC, LRUN, QG) do {                                         \
    const float rinv = 1.0f / LRUN;                                        \
    float* orow = out + ((bs_off + (QG)) * HH + h) * DD;                   \
    _Pragma("unroll")                                                      \
    for (int m = 0; m < 4; ++m)                                            \
      _Pragma("unroll")                                                    \
      for (int rq = 0; rq < 4; ++rq) {                                     \
        float4 o;                                                          \
        o.x = ACC[m][4 * rq + 0] * rinv;                                   \
        o.y = ACC[m][4 * rq + 1] * rinv;                                   \
        o.z = ACC[m][4 * rq + 2] * rinv;                                   \
        o.w = ACC[m][4 * rq + 3] * rinv;                                   \
        *(float4*)(orow + m * 32 + 8 * rq + 4 * hi) = o;                   \
      } } while(0)

  EPILOG(accA, lrunA, qgA);
  EPILOG(accB, lrunB, qgB);
#undef STAGE_T
#undef LOADQ
#undef SOFTMAX1
#undef PFRAG
#undef APPLY_BIAS
#undef APPLY_MASK
#undef EPILOG
}

// =====================================================================
extern "C" void kernel_launch(void* const* d_in, const int* in_sizes, int n_in,
                              void* d_out, int out_size, void* d_ws, size_t ws_size,
                              hipStream_t stream)
{
  const float* query  = (const float*)d_in[0];
  const float* key    = (const float*)d_in[1];
  const float* value  = (const float*)d_in[2];
  const float* kc_in  = (const float*)d_in[3];
  const float* vc_in  = (const float*)d_in[4];
  const int*   bidx   = (const int*)d_in[5];
  const float* slopes = (const float*)d_in[6];
  const int n_used = in_sizes[5];

  float* out_attn = (float*)d_out;
  float* kc_out   = out_attn + (size_t)BB * SS * HH * DD;
  float* vc_out   = kc_out + (size_t)NBLK * PAGE * HKV * DD;

  unsigned char* kpk = (unsigned char*)d_ws;                       // 16.8 MB
  unsigned char* vpk = kpk + (size_t)BB * HKV * SS * DD * 2;       // 16.8 MB

  hipLaunchKernelGGL(pack_kv_kernel, dim3(BB * HKV * (SS / 64)), dim3(256), 0, stream,
                     key, value, kpk, vpk);
  hipLaunchKernelGGL(attn_kernel, dim3(512), dim3(256), 0, stream,
                     query, kpk, vpk, slopes, out_attn);
  hipLaunchKernelGGL(cache_scatter_kernel, dim3(NBLK * 2 * 8), dim3(256), 0, stream,
                     key, value, kc_in, vc_in, bidx, n_used, kc_out, vc_out);
}

// Round 12
// 115.392 us; speedup vs baseline: 1.3046x; 1.3046x over previous
//
#include <hip/hip_runtime.h>
#include <hip/hip_bf16.h>
#include <type_traits>
#include <stdint.h>

// ---- problem constants ----
static constexpr int BB   = 4;
static constexpr int SS   = 1024;
static constexpr int HH   = 32;
static constexpr int HKV  = 8;
static constexpr int GG   = 4;      // H / HKV
static constexpr int DD   = 128;
static constexpr int PAGE = 128;    // paged-cache block size
static constexpr int NBLK = 64;     // cache blocks
static constexpr int QBLK = 128;    // q rows per q-tile (4 waves x 32)
static constexpr int KVB  = 32;     // kv rows per tile
static constexpr int NT   = SS / KVB;   // 32 kv tiles per (b,hkv)
static constexpr int TB   = 8192;   // packed tile bytes ([32 rows][256B])
static constexpr int PACK_BLOCKS = BB * HKV * (SS / 64);    // 512
static constexpr int SCAT_BLOCKS = NBLK * 2 * 8;            // 1024

typedef __attribute__((ext_vector_type(8)))  short    s16x8;
typedef __attribute__((ext_vector_type(8)))  __bf16   b16x8;
typedef __attribute__((ext_vector_type(16))) float    f32x16;
typedef __attribute__((ext_vector_type(4)))  unsigned u32x4;

// ---- MFMA wrapper: compiles whether the builtin takes short8 or bf16x8 ----
template <typename T>
__device__ __forceinline__ auto mfma_try(T a, T b, f32x16 c, int)
    -> decltype(__builtin_amdgcn_mfma_f32_32x32x16_bf16(a, b, c, 0, 0, 0)) {
  return __builtin_amdgcn_mfma_f32_32x32x16_bf16(a, b, c, 0, 0, 0);
}
template <typename T>
__device__ __forceinline__ f32x16 mfma_try(T a, T b, f32x16 c, long) {
  using O = typename std::conditional<std::is_same<T, s16x8>::value, b16x8, s16x8>::type;
  return __builtin_amdgcn_mfma_f32_32x32x16_bf16(
      __builtin_bit_cast(O, a), __builtin_bit_cast(O, b), c, 0, 0, 0);
}
__device__ __forceinline__ f32x16 mfma32_bf16(s16x8 a, s16x8 b, f32x16 c) {
  return mfma_try(a, b, c, 0);
}

__device__ __forceinline__ short bfb(float x) {
  return (short)__builtin_bit_cast(unsigned short, (__bf16)x);
}
__device__ __forceinline__ unsigned pack_bf16x2(float a, float b) {
  unsigned ua = (unsigned short)__builtin_bit_cast(unsigned short, (__bf16)a);
  unsigned ub = (unsigned short)__builtin_bit_cast(unsigned short, (__bf16)b);
  return ua | (ub << 16);
}
__device__ __forceinline__ f32x16 zero16() {
  f32x16 z;
#pragma unroll
  for (int i = 0; i < 16; ++i) z[i] = 0.0f;
  return z;
}
__device__ __forceinline__ void gload16(const unsigned char* g, unsigned char* l) {
  __builtin_amdgcn_global_load_lds(
      (const __attribute__((address_space(1))) unsigned*)g,
      (__attribute__((address_space(3))) unsigned*)(unsigned*)l, 16, 0, 0);
}
#define VC(a, i) ((i)==0?(a).x:(i)==1?(a).y:(i)==2?(a).z:(a).w)

// =====================================================================
// Kernel 0 (merged prep): blocks [0,512) pack K/V into swizzled bf16
// tiles (identical layout to R5-R11's pack_kv_kernel); blocks [512,1536)
// do the paged-cache scatter (identical to R4-R9's cache_scatter_kernel).
// One dispatch: removes a launch gap; pack's k/v reads warm L3 for the
// scatter's re-reads of the same data.
// =====================================================================
__global__ void __launch_bounds__(256)
prep_kernel(const float* __restrict__ k_in, const float* __restrict__ v_in,
            const float* __restrict__ kc_in, const float* __restrict__ vc_in,
            const int* __restrict__ bidx, int n_used,
            float* __restrict__ kc_out, float* __restrict__ vc_out,
            unsigned char* __restrict__ kpk, unsigned char* __restrict__ vpk)
{
  __shared__ __align__(16) unsigned char Vt[DD * 176];  // [d][64 kv], stride 176B
  const int nblk = blockIdx.x;
  const int tid  = threadIdx.x;

  if (nblk >= PACK_BLOCKS) {
    // ================= scatter role =================
    const int wg    = nblk - PACK_BLOCKS;
    const int BLK_ELEMS = PAGE * HKV * DD;
    const int chunk = wg & 7;
    const int which = (wg >> 3) & 1;
    const int cb    = wg >> 4;

    int src_blk = -1;
    for (int i = 0; i < n_used; ++i)
      if (bidx[i] == cb) src_blk = i;      // last match wins

    const float* src;
    float* dst;
    if (which == 0) {
      src = (src_blk >= 0) ? (k_in + (size_t)src_blk * BLK_ELEMS)
                           : (kc_in + (size_t)cb * BLK_ELEMS);
      dst = kc_out + (size_t)cb * BLK_ELEMS;
    } else {
      src = (src_blk >= 0) ? (v_in + (size_t)src_blk * BLK_ELEMS)
                           : (vc_in + (size_t)cb * BLK_ELEMS);
      dst = vc_out + (size_t)cb * BLK_ELEMS;
    }
    const int CHUNK = BLK_ELEMS / 8;
    const float4* s4 = (const float4*)(src + chunk * CHUNK);
    float4*       d4 = (float4*)(dst + chunk * CHUNK);
#pragma unroll 4
    for (int i = tid; i < CHUNK / 4; i += 256) d4[i] = s4[i];
    return;
  }

  // ================= pack role (verified R5-R11 layout) =================
  const int wg  = nblk;                // (b*HKV+hkv)*16 + t64
  const int t64 = wg & 15;
  const int bh  = wg >> 4;             // b*HKV + hkv
  const int row = tid >> 2, c = tid & 3;

  const size_t srow = ((size_t)(bh >> 3) * SS + t64 * 64 + row) * (HKV * DD)
                    + (size_t)(bh & 7) * DD + c * 32;
  const size_t tb0 = ((size_t)bh * NT + t64 * 2) * (size_t)TB;

  // ---- K: bf16 pack, swizzled chunk placement ----
  {
    const float* ks = k_in + srow;
    const int t2 = row >> 5, r32 = row & 31;
    unsigned char* kd = kpk + tb0 + t2 * TB + r32 * 256;
#pragma unroll
    for (int j = 0; j < 4; ++j) {
      const float4 f0 = *(const float4*)(ks + j * 8);
      const float4 f1 = *(const float4*)(ks + j * 8 + 4);
      s16x8 kb;
      kb[0]=bfb(f0.x); kb[1]=bfb(f0.y); kb[2]=bfb(f0.z); kb[3]=bfb(f0.w);
      kb[4]=bfb(f1.x); kb[5]=bfb(f1.y); kb[6]=bfb(f1.z); kb[7]=bfb(f1.w);
      *(s16x8*)(kd + (((c * 4 + j) ^ (r32 & 15)) << 4)) = kb;
    }
  }
  // ---- V: transpose via LDS ----
  {
    const float* vs = v_in + srow;
    float4 va[8];
#pragma unroll
    for (int jj = 0; jj < 8; ++jj) va[jj] = *(const float4*)(vs + jj * 4);
#pragma unroll
    for (int jj = 0; jj < 8; ++jj)
#pragma unroll
      for (int e = 0; e < 4; ++e) {
        const int d = c * 32 + jj * 4 + e;
        *(short*)(Vt + d * 176 + row * 2) = bfb(VC(va[jj], e));
      }
  }
  __syncthreads();
  {
    const int t2 = tid & 1, r = (tid >> 1) & 31, q = tid >> 6;
    unsigned char* vd = vpk + tb0 + t2 * TB + r * 256;
#pragma unroll
    for (int jj = 0; jj < 4; ++jj) {
      const int lc = q * 4 + jj;
      const int d  = (lc >> 2) * 32 + r;
      const float4 chunk = *(const float4*)(Vt + d * 176 + t2 * 64 + (lc & 3) * 16);
      *(float4*)(vd + ((lc ^ (r & 15)) << 4)) = chunk;
    }
  }
}

// =====================================================================
// Kernel 2: causal + ALiBi GQA prefill attention, bf16 MFMA 32x32x16.
// R9 VERBATIM (best verified: 93 us).  KVB=32, 4 waves/wg, 3 wg/CU.
// 3-buffer LDS rotation, prefetch distance 2, counted vmcnt(4) + raw
// s_barrier per phase (never drain to 0 in the main loop).
// =====================================================================
__global__ void __launch_bounds__(256, 3)
attn_kernel(const float* __restrict__ q_in,
            const unsigned char* __restrict__ kpk,
            const unsigned char* __restrict__ vpk,
            const float* __restrict__ slopes, float* __restrict__ out)
{
  __shared__ __align__(16) unsigned char K_lds[3][TB];  // 3 x 8 KB
  __shared__ __align__(16) unsigned char V_lds[3][TB];  // 3 x 8 KB

  const int n   = blockIdx.x;            // 0..1023
  const int tid = threadIdx.x;
  const int xcd = n & 7;
  const int p   = n >> 3;                // 0..127, ascending dispatch
  const int qt  = 7 - (p >> 4);          // big q-tiles launch first
  const int hc  = xcd * 16 + (p & 15);   // head-combo, XCD-local KV reuse
  const int b   = hc >> 5;
  const int hkv = (hc >> 2) & 7;
  const int g   = hc & 3;
  const int h   = hkv * GG + g;

  const int w    = tid >> 6;
  const int lane = tid & 63;
  const int ln   = lane & 31;
  const int hi   = lane >> 5;

  const float LOG2E  = 1.44269504088896340736f;
  const float QSCALE = 0.08838834764831845f * LOG2E;
  const float slope2 = slopes[h] * LOG2E;

  // staging roles: waves 0,1 -> K halves; waves 2,3 -> V halves (4 loads/tile)
  const size_t bh_off = (size_t)(b * HKV + hkv) * NT * (size_t)TB;
  const int role_v = w >> 1, halfid = w & 1;
  const unsigned char* gsrc = (role_v ? vpk : kpk) + bh_off
                            + halfid * 4096 + (size_t)lane * 16;
  unsigned char* ldst = (role_v ? &V_lds[0][0] : &K_lds[0][0])
                      + halfid * 4096 + lane * 16;

#define STAGE(T, B) do { if ((T) < nt) {                                   \
    const unsigned char* g_ = gsrc + (size_t)(T) * TB;                     \
    unsigned char* l_ = ldst + (B) * TB;                                   \
    gload16(g_, l_);               gload16(g_ + 1024, l_ + 1024);          \
    gload16(g_ + 2048, l_ + 2048); gload16(g_ + 3072, l_ + 3072); } } while(0)

  const int lnbase = ln * 256;
  const int lnsw   = (ln & 15) << 4;
  const int hib    = hi * 16;

  const int qb    = qt * QBLK;
  const int qw0   = qb + w * 32;         // wave's first q row
  const int qg    = qw0 + ln;
  const int nt    = 4 * qt + 4;
  const int tmax  = (qw0 + 31) >> 5;     // last tile this wave computes
  const int tdiag = qw0 >> 5;            // diagonal tile index
  const size_t bs_off = (size_t)b * SS;

  // ---- Q fragments, pre-scaled (complete before the loop) ----
  s16x8 qfrag[8];
  {
    const float* qrow = q_in + ((bs_off + qg) * HH + h) * DD;
#pragma unroll
    for (int ks = 0; ks < 8; ++ks) {
      const float4 f0 = *(const float4*)(qrow + ks * 16 + hi * 8);
      const float4 f1 = *(const float4*)(qrow + ks * 16 + hi * 8 + 4);
      s16x8 qv;
      qv[0] = bfb(f0.x * QSCALE); qv[1] = bfb(f0.y * QSCALE);
      qv[2] = bfb(f0.z * QSCALE); qv[3] = bfb(f0.w * QSCALE);
      qv[4] = bfb(f1.x * QSCALE); qv[5] = bfb(f1.y * QSCALE);
      qv[6] = bfb(f1.z * QSCALE); qv[7] = bfb(f1.w * QSCALE);
      qfrag[ks] = qv;
    }
  }

  f32x16 acc[4];
#pragma unroll
  for (int m = 0; m < 4; ++m) acc[m] = zero16();
  float mrun = -INFINITY, lrun = 0.0f;

  // ---- prologue: two tiles in flight ----
  STAGE(0, 0);
  STAGE(1, 1);

  int b0 = 0;                            // buffer of tile t
  for (int t = 0; t < nt; ++t) {
    // tile t's loads done (4 newest = tile t+1's may stay in flight)
    if (t + 1 < nt) asm volatile("s_waitcnt vmcnt(4)" ::: "memory");
    else            asm volatile("s_waitcnt vmcnt(0)" ::: "memory");
    __builtin_amdgcn_s_barrier();        // publish LDS; all waves in phase t
    __builtin_amdgcn_sched_barrier(0);   // no ds_read hoisting above barrier

    int b2 = b0 + 2; if (b2 >= 3) b2 -= 3;
    STAGE(t + 2, b2);                    // buf freed by phase t-1 (barrier-proven)

    if (t <= tmax) {
      const unsigned char* kb = &K_lds[0][0] + b0 * TB;
      const unsigned char* vb = &V_lds[0][0] + b0 * TB;

      // ---- S^T = K * Q^T (one 32x32 tile) ----
      f32x16 sc;
      {
        f32x16 a = zero16();
        const unsigned char* krow = kb + lnbase;
        __builtin_amdgcn_s_setprio(1);
#pragma unroll
        for (int ks = 0; ks < 8; ++ks) {
          const s16x8 af = *(const s16x8*)(krow + ((ks * 32 + hib) ^ lnsw));
          a = mfma32_bf16(af, qfrag[ks], a);
        }
        __builtin_amdgcn_s_setprio(0);
        sc = a;
      }

      // ---- ALiBi bias (q-term dropped: softmax-invariant) ----
      const float kbasef = (float)(t * KVB + 4 * hi);
#pragma unroll
      for (int r = 0; r < 16; ++r) {
        const float patc = (float)((r & 3) + 8 * (r >> 2));
        sc[r] = __builtin_fmaf(slope2, kbasef + patc, sc[r]);
      }
      if (t == tdiag) {                  // single diagonal tile: mask
#pragma unroll
        for (int r = 0; r < 16; ++r) {
          const int pat = (r & 3) + 8 * (r >> 2) + 4 * hi;
          sc[r] = (pat <= ln) ? sc[r] : -INFINITY;
        }
      }

      // ---- max tree (max3-shaped) + shfl cross-half merge ----
      const float a0 = fmaxf(fmaxf(sc[0], sc[1]), sc[2]);
      const float a1 = fmaxf(fmaxf(sc[3], sc[4]), sc[5]);
      const float a2 = fmaxf(fmaxf(sc[6], sc[7]), sc[8]);
      const float a3 = fmaxf(fmaxf(sc[9], sc[10]), sc[11]);
      const float a4 = fmaxf(fmaxf(sc[12], sc[13]), sc[14]);
      const float bm0 = fmaxf(fmaxf(a0, a1), sc[15]);
      const float bm1 = fmaxf(fmaxf(a2, a3), a4);
      float pm = fmaxf(bm0, bm1);
      pm = fmaxf(pm, __shfl_xor(pm, 32));

      // ---- defer-max: rescale only when max grew past THR ----
      if (!__all(pm <= mrun + 8.0f)) {
        const float mnew = fmaxf(mrun, pm);
        const float fac  = __builtin_exp2f(mrun - mnew);
        lrun *= fac;
#pragma unroll
        for (int m = 0; m < 4; ++m)
#pragma unroll
          for (int r = 0; r < 16; ++r) acc[m][r] *= fac;
        mrun = mnew;
      }

      // ---- exp2 + tree sum (shfl merge) ----
#pragma unroll
      for (int r = 0; r < 16; ++r) sc[r] = __builtin_exp2f(sc[r] - mrun);
      float s8[8];
#pragma unroll
      for (int i = 0; i < 8; ++i) s8[i] = sc[i] + sc[i + 8];
#pragma unroll
      for (int i = 0; i < 4; ++i) s8[i] = s8[i] + s8[i + 4];
      float rs = (s8[0] + s8[1]) + (s8[2] + s8[3]);
      rs += __shfl_xor(rs, 32);
      lrun += rs;

      // ---- O^T += V^T * P^T; P frags via hi-preselected shfl (verified) ----
      __builtin_amdgcn_s_setprio(1);
#pragma unroll
      for (int ks2 = 0; ks2 < 2; ++ks2) {
        const unsigned u0 = pack_bf16x2(sc[8 * ks2 + 0], sc[8 * ks2 + 1]);
        const unsigned u1 = pack_bf16x2(sc[8 * ks2 + 2], sc[8 * ks2 + 3]);
        const unsigned u2 = pack_bf16x2(sc[8 * ks2 + 4], sc[8 * ks2 + 5]);
        const unsigned u3 = pack_bf16x2(sc[8 * ks2 + 6], sc[8 * ks2 + 7]);
        const unsigned aa0 = hi ? u0 : u2;
        const unsigned aa1 = hi ? u1 : u3;
        const unsigned x0 = __shfl_xor(aa0, 32);
        const unsigned x1 = __shfl_xor(aa1, 32);
        const unsigned f0 = hi ? x0 : u0;
        const unsigned f1 = hi ? x1 : u1;
        const unsigned f2 = hi ? u2 : x0;
        const unsigned f3 = hi ? u3 : x1;
        const u32x4 fw = {f0, f1, f2, f3};
        const s16x8 pfrag = __builtin_bit_cast(s16x8, fw);
#pragma unroll
        for (int m = 0; m < 4; ++m) {
          const s16x8 vf = *(const s16x8*)(vb + lnbase +
                               ((m * 64 + ks2 * 32 + hib) ^ lnsw));
          acc[m] = mfma32_bf16(vf, pfrag, acc[m]);
        }
      }
      __builtin_amdgcn_s_setprio(0);
    }

    b0 = (b0 + 1 == 3) ? 0 : b0 + 1;
  }

  // ---- epilogue: O = O^T / l ----
  const float rinv = 1.0f / lrun;
  float* orow = out + ((bs_off + qg) * HH + h) * DD;
#pragma unroll
  for (int m = 0; m < 4; ++m)
#pragma unroll
    for (int rq = 0; rq < 4; ++rq) {
      float4 o;
      o.x = acc[m][4 * rq + 0] * rinv;
      o.y = acc[m][4 * rq + 1] * rinv;
      o.z = acc[m][4 * rq + 2] * rinv;
      o.w = acc[m][4 * rq + 3] * rinv;
      *(float4*)(orow + m * 32 + 8 * rq + 4 * hi) = o;
    }
#undef STAGE
}

// =====================================================================
extern "C" void kernel_launch(void* const* d_in, const int* in_sizes, int n_in,
                              void* d_out, int out_size, void* d_ws, size_t ws_size,
                              hipStream_t stream)
{
  const float* query  = (const float*)d_in[0];
  const float* key    = (const float*)d_in[1];
  const float* value  = (const float*)d_in[2];
  const float* kc_in  = (const float*)d_in[3];
  const float* vc_in  = (const float*)d_in[4];
  const int*   bidx   = (const int*)d_in[5];
  const float* slopes = (const float*)d_in[6];
  const int n_used = in_sizes[5];

  float* out_attn = (float*)d_out;
  float* kc_out   = out_attn + (size_t)BB * SS * HH * DD;
  float* vc_out   = kc_out + (size_t)NBLK * PAGE * HKV * DD;

  unsigned char* kpk = (unsigned char*)d_ws;                       // 16.8 MB
  unsigned char* vpk = kpk + (size_t)BB * HKV * SS * DD * 2;       // 16.8 MB

  hipLaunchKernelGGL(prep_kernel, dim3(PACK_BLOCKS + SCAT_BLOCKS), dim3(256), 0, stream,
                     key, value, kc_in, vc_in, bidx, n_used, kc_out, vc_out, kpk, vpk);
  hipLaunchKernelGGL(attn_kernel, dim3(BB * HKV * GG * 8), dim3(256), 0, stream,
                     query, kpk, vpk, slopes, out_attn);
}